// Round 1
// baseline (100192.480 us; speedup 1.0000x reference)
//
#include <hip/hip_runtime.h>

#define S 1024
#define NOBS 4096
#define TSTEPS 8192
#define NWG 64
#define COLS 16   // output columns per WG: NWG*COLS == S
#define NTHR 512  // 8 waves

typedef __attribute__((ext_vector_type(8))) _Float16 half8;

#define AGENT __HIP_MEMORY_SCOPE_AGENT

__device__ __forceinline__ float wmaxred(float v) {
#pragma unroll
  for (int off = 32; off > 0; off >>= 1) v = fmaxf(v, __shfl_xor(v, off, 64));
  return v;
}
__device__ __forceinline__ float wsumred(float v) {
#pragma unroll
  for (int off = 32; off > 0; off >>= 1) v += __shfl_xor(v, off, 64);
  return v;
}

// One-time: Et[j][i] = exp(trans[i][j])  (transposed, fp16) via LDS tile transpose.
__global__ void prep_E(const float* __restrict__ trans, _Float16* __restrict__ Et) {
  __shared__ float tile[32][33];
  const int tx = threadIdx.x, ty = threadIdx.y;
  const int bi = blockIdx.y, bj = blockIdx.x;
  tile[ty][tx] = trans[(size_t)(bi * 32 + ty) * S + bj * 32 + tx];
  __syncthreads();
  // write Et[j' = bj*32+ty][i' = bi*32+tx] = exp(trans[i'][j']) = exp(tile[tx][ty])
  Et[(size_t)(bj * 32 + ty) * S + bi * 32 + tx] = (_Float16)__expf(tile[tx][ty]);
}

// One-time: r0 = start + emit[:, obs[0]]; per-chunk partial maxes; reset barrier.
__global__ void hmm_init(const int* __restrict__ obs, const float* __restrict__ start,
                         const float* __restrict__ emit, float* rbuf, float* pmax,
                         int* cnt) {
  const int tid = threadIdx.x;  // 1024 threads
  const int o0 = obs[0];
  const float r = start[tid] + emit[(size_t)tid * NOBS + o0];
  rbuf[tid] = r;  // buffer 0; kernel boundary publishes
  __shared__ float sm[S];
  sm[tid] = r;
  __syncthreads();
  if (tid < NWG) {
    float mx = sm[tid * COLS];
#pragma unroll
    for (int k = 1; k < COLS; ++k) mx = fmaxf(mx, sm[tid * COLS + k]);
    pmax[tid] = mx;  // buffer 0
  }
  if (tid == 0) *cnt = 0;
}

__global__ __launch_bounds__(NTHR) void hmm_main(
    const int* __restrict__ obs, const float* __restrict__ emit,
    const _Float16* __restrict__ Et, float* rbuf, float* pmax, int* cnt,
    float* __restrict__ out) {
  __shared__ _Float16 Es[COLS * S];  // 32 KB: this WG's 16 columns of E (as [col][i])
  __shared__ float p[S];             // 4 KB
  __shared__ float rcol[COLS];
  __shared__ float earr[COLS];
  __shared__ float redbuf[NTHR / 64];
  __shared__ float m_sh;
  const int tid = threadIdx.x;
  const int lane = tid & 63;
  const int wave = tid >> 6;
  const int wg = blockIdx.x;

  {  // stage E slice, coalesced 16B loads
    const int4* src = (const int4*)(Et + (size_t)wg * COLS * S);
    int4* dst = (int4*)Es;
#pragma unroll
    for (int k = 0; k < (COLS * S / 8) / NTHR; ++k)  // 4 iters
      dst[k * NTHR + tid] = src[k * NTHR + tid];
  }
  __syncthreads();

  double c = 0.0;  // accumulated scale offset (double: 8192 adds of ~|5| each)
  int cur = 0;
  for (int t = 1; t < TSTEPS; ++t) {
    // prefetch this step's emit values (independent of r) — wave 1, lanes 0..15
    if (wave == 1 && lane < COLS) {
      const int ot = obs[t];
      earr[lane] = emit[(size_t)(wg * COLS + lane) * NOBS + ot];
    }
    // read previous-step r (device-coherent loads)
    float rv0 = __hip_atomic_load(&rbuf[cur * S + tid], __ATOMIC_RELAXED, AGENT);
    float rv1 = __hip_atomic_load(&rbuf[cur * S + tid + NTHR], __ATOMIC_RELAXED, AGENT);
    // m = max over 64 partial maxes (written last step), reduced by wave 0
    if (wave == 0) {
      float v = __hip_atomic_load(&pmax[cur * NWG + lane], __ATOMIC_RELAXED, AGENT);
      v = wmaxred(v);
      if (lane == 0) m_sh = v;
    }
    __syncthreads();
    const float m = m_sh;
    p[tid] = __expf(rv0 - m);
    p[tid + NTHR] = __expf(rv1 - m);
    __syncthreads();
    // dot products: wave w handles local columns 2w, 2w+1; lane covers i in [16*lane, 16*lane+16)
#pragma unroll
    for (int cc = 0; cc < 2; ++cc) {
      const int jl = wave * 2 + cc;
      const float* pl = p + lane * 16;
      const _Float16* el = Es + jl * S + lane * 16;
      const float4 pa = ((const float4*)pl)[0];
      const float4 pb = ((const float4*)pl)[1];
      const float4 pc2 = ((const float4*)pl)[2];
      const float4 pd = ((const float4*)pl)[3];
      const half8 h0 = ((const half8*)el)[0];
      const half8 h1 = ((const half8*)el)[1];
      float acc =
          pa.x * (float)h0[0] + pa.y * (float)h0[1] + pa.z * (float)h0[2] + pa.w * (float)h0[3] +
          pb.x * (float)h0[4] + pb.y * (float)h0[5] + pb.z * (float)h0[6] + pb.w * (float)h0[7] +
          pc2.x * (float)h1[0] + pc2.y * (float)h1[1] + pc2.z * (float)h1[2] + pc2.w * (float)h1[3] +
          pd.x * (float)h1[4] + pd.y * (float)h1[5] + pd.z * (float)h1[6] + pd.w * (float)h1[7];
      acc = wsumred(acc);
      if (lane == 0) {
        const float rn = __logf(acc) + earr[jl];
        rcol[jl] = rn;
        __hip_atomic_store(&rbuf[(cur ^ 1) * S + wg * COLS + jl], rn, __ATOMIC_RELEASE, AGENT);
      }
    }
    c += (double)m;
    __syncthreads();  // all waves' r stores drained (vmcnt(0) before s_barrier)
    if (tid == 0) {
      float mx = rcol[0];
#pragma unroll
      for (int k = 1; k < COLS; ++k) mx = fmaxf(mx, rcol[k]);
      __hip_atomic_store(&pmax[(cur ^ 1) * NWG + wg], mx, __ATOMIC_RELEASE, AGENT);
      __hip_atomic_fetch_add(cnt, 1, __ATOMIC_ACQ_REL, AGENT);
      const int target = NWG * t;  // monotone counter: no reset, no sense reversal
      while (__hip_atomic_load(cnt, __ATOMIC_ACQUIRE, AGENT) < target)
        __builtin_amdgcn_s_sleep(1);
    }
    __syncthreads();
    cur ^= 1;
  }

  // final logsumexp by WG 0
  if (wg == 0) {
    const float rv0 = __hip_atomic_load(&rbuf[cur * S + tid], __ATOMIC_RELAXED, AGENT);
    const float rv1 = __hip_atomic_load(&rbuf[cur * S + tid + NTHR], __ATOMIC_RELAXED, AGENT);
    float mx = wmaxred(fmaxf(rv0, rv1));
    if (lane == 0) redbuf[wave] = mx;
    __syncthreads();
    if (tid == 0) {
      float g = redbuf[0];
#pragma unroll
      for (int k = 1; k < NTHR / 64; ++k) g = fmaxf(g, redbuf[k]);
      m_sh = g;
    }
    __syncthreads();
    const float g = m_sh;
    float s2 = __expf(rv0 - g) + __expf(rv1 - g);
    s2 = wsumred(s2);
    __syncthreads();
    if (lane == 0) redbuf[wave] = s2;
    __syncthreads();
    if (tid == 0) {
      float tot = redbuf[0];
#pragma unroll
      for (int k = 1; k < NTHR / 64; ++k) tot += redbuf[k];
      out[0] = (float)(c + (double)g + (double)__logf(tot));
    }
  }
}

extern "C" void kernel_launch(void* const* d_in, const int* in_sizes, int n_in,
                              void* d_out, int out_size, void* d_ws, size_t ws_size,
                              hipStream_t stream) {
  const int* obs = (const int*)d_in[0];
  const float* start = (const float*)d_in[1];
  const float* trans = (const float*)d_in[2];
  const float* emit = (const float*)d_in[3];

  // ws layout: [0] int counter | 256: pmax[2][64] f32 | 1024: rbuf[2][1024] f32 | 16384: Et 1024*1024 fp16
  int* cnt = (int*)d_ws;
  float* pmax = (float*)((char*)d_ws + 256);
  float* rbuf = (float*)((char*)d_ws + 1024);
  _Float16* Et = (_Float16*)((char*)d_ws + 16384);

  prep_E<<<dim3(32, 32), dim3(32, 32), 0, stream>>>(trans, Et);
  hmm_init<<<1, S, 0, stream>>>(obs, start, emit, rbuf, pmax, cnt);
  hmm_main<<<NWG, NTHR, 0, stream>>>(obs, emit, Et, rbuf, pmax, cnt, (float*)d_out);
}

// Round 2
// 21561.670 us; speedup vs baseline: 4.6468x; 4.6468x over previous
//
#include <hip/hip_runtime.h>

#define S 1024
#define NOBS 4096
#define TSTEPS 8192
#define NWG 64
#define COLS 16   // output columns per WG: NWG*COLS == S
#define NTHR 512  // 8 waves
#define NWAVE (NTHR / 64)

#define AGENT __HIP_MEMORY_SCOPE_AGENT

typedef __attribute__((ext_vector_type(4))) _Float16 half4;

__device__ __forceinline__ float wmaxred(float v) {
#pragma unroll
  for (int off = 32; off > 0; off >>= 1) v = fmaxf(v, __shfl_xor(v, off, 64));
  return v;
}
__device__ __forceinline__ float wsumred(float v) {
#pragma unroll
  for (int off = 32; off > 0; off >>= 1) v += __shfl_xor(v, off, 64);
  return v;
}

// One-time: Et[j][i] = exp(trans[i][j])  (transposed, fp16) via LDS tile transpose.
__global__ void prep_E(const float* __restrict__ trans, _Float16* __restrict__ Et) {
  __shared__ float tile[32][33];
  const int tx = threadIdx.x, ty = threadIdx.y;
  const int bi = blockIdx.y, bj = blockIdx.x;
  tile[ty][tx] = trans[(size_t)(bi * 32 + ty) * S + bj * 32 + tx];
  __syncthreads();
  Et[(size_t)(bj * 32 + ty) * S + bi * 32 + tx] = (_Float16)__expf(tile[tx][ty]);
}

// One-time: r0 = start + emit[:, obs[0]] packed with tag 0 into buffer 0.
__global__ void hmm_init(const int* __restrict__ obs, const float* __restrict__ start,
                         const float* __restrict__ emit, unsigned long long* rbuf) {
  const int tid = threadIdx.x;  // 1024 threads
  const float r = start[tid] + emit[(size_t)tid * NOBS + obs[0]];
  const unsigned long long u = (unsigned long long)__float_as_uint(r);  // tag 0 in hi32
  __hip_atomic_store(&rbuf[tid], u, __ATOMIC_RELAXED, AGENT);
}

__device__ __forceinline__ void spin2(const unsigned long long* src, int i0, int i1,
                                      int tag, float& v0, float& v1) {
  bool ok0 = false, ok1 = false;
  v0 = 0.f; v1 = 0.f;
  while (!(ok0 && ok1)) {
    if (!ok0) {
      unsigned long long u = __hip_atomic_load(&src[i0], __ATOMIC_RELAXED, AGENT);
      if ((int)(u >> 32) == tag) { v0 = __uint_as_float((unsigned)u); ok0 = true; }
    }
    if (!ok1) {
      unsigned long long u = __hip_atomic_load(&src[i1], __ATOMIC_RELAXED, AGENT);
      if ((int)(u >> 32) == tag) { v1 = __uint_as_float((unsigned)u); ok1 = true; }
    }
  }
}

__global__ __launch_bounds__(NTHR) void hmm_main(
    const int* __restrict__ obs, const float* __restrict__ emit,
    const _Float16* __restrict__ Et, unsigned long long* rbuf,
    float* __restrict__ out) {
  __shared__ float p[S];            // 4 KB
  __shared__ float wred[NWAVE];
  __shared__ float earr[COLS];
  const int tid = threadIdx.x;
  const int lane = tid & 63;
  const int wave = tid >> 6;
  const int wg = blockIdx.x;

  // E fragments in registers: wave w owns columns 2w, 2w+1; lane L owns
  // i in {256k + 4L .. 256k + 4L + 3 | k=0..3}.  32 VGPRs.
  float4 er[2][4];
#pragma unroll
  for (int cc = 0; cc < 2; ++cc) {
#pragma unroll
    for (int k = 0; k < 4; ++k) {
      const _Float16* src = Et + (size_t)(wg * COLS + wave * 2 + cc) * S + k * 256 + lane * 4;
      const half4 h = *(const half4*)src;
      er[cc][k] = make_float4((float)h[0], (float)h[1], (float)h[2], (float)h[3]);
    }
  }

  double c = 0.0;  // accumulated scale offset; identical in every thread
  const int i0 = tid, i1 = tid + NTHR;

  for (int t = 1; t < TSTEPS; ++t) {
    // emit gather for this step — issued before the spin so latency overlaps it
    float ev = 0.f;
    if (wave == 1 && lane < COLS) {
      const int ot = obs[t];
      ev = emit[(size_t)(wg * COLS + lane) * NOBS + ot];
    }
    const int tm1 = t - 1;
    const unsigned long long* src = rbuf + ((tm1 & 1) ? S : 0);
    float v0, v1;
    spin2(src, i0, i1, tm1, v0, v1);

    // local max over all 1024 r values (bit-identical in every WG)
    const float ml = wmaxred(fmaxf(v0, v1));
    if (lane == 0) wred[wave] = ml;
    __syncthreads();  // barrier 1
    float m = wred[0];
#pragma unroll
    for (int k = 1; k < NWAVE; ++k) m = fmaxf(m, wred[k]);

    p[i0] = __expf(v0 - m);
    p[i1] = __expf(v1 - m);
    if (wave == 1 && lane < COLS) earr[lane] = ev;
    __syncthreads();  // barrier 2

    // dot: lane-contiguous b128 reads of p (conflict-free), E in registers
    float acc0 = 0.f, acc1 = 0.f;
    const float4* p4 = (const float4*)p;
#pragma unroll
    for (int k = 0; k < 4; ++k) {
      const float4 pv = p4[k * 64 + lane];
      acc0 += pv.x * er[0][k].x + pv.y * er[0][k].y + pv.z * er[0][k].z + pv.w * er[0][k].w;
      acc1 += pv.x * er[1][k].x + pv.y * er[1][k].y + pv.z * er[1][k].z + pv.w * er[1][k].w;
    }
    acc0 = wsumred(acc0);
    acc1 = wsumred(acc1);
    c += (double)m;

    unsigned long long* dst = rbuf + ((t & 1) ? S : 0);
    if (lane == 0) {
      const float rn0 = __logf(acc0) + earr[wave * 2 + 0];
      const float rn1 = __logf(acc1) + earr[wave * 2 + 1];
      const unsigned long long tg = (unsigned long long)(unsigned)t << 32;
      __hip_atomic_store(&dst[wg * COLS + wave * 2 + 0],
                         tg | (unsigned)__float_as_uint(rn0), __ATOMIC_RELAXED, AGENT);
      __hip_atomic_store(&dst[wg * COLS + wave * 2 + 1],
                         tg | (unsigned)__float_as_uint(rn1), __ATOMIC_RELAXED, AGENT);
    }
  }

  // final logsumexp by WG 0 over r_{T-1}
  if (wg == 0) {
    const int tf = TSTEPS - 1;
    const unsigned long long* src = rbuf + ((tf & 1) ? S : 0);
    float v0, v1;
    spin2(src, i0, i1, tf, v0, v1);
    float g = wmaxred(fmaxf(v0, v1));
    if (lane == 0) wred[wave] = g;
    __syncthreads();
    g = wred[0];
#pragma unroll
    for (int k = 1; k < NWAVE; ++k) g = fmaxf(g, wred[k]);
    float s = wsumred(__expf(v0 - g) + __expf(v1 - g));
    if (lane == 0) earr[wave] = s;  // reuse earr as sum buffer (16 slots >= 8)
    __syncthreads();
    if (tid == 0) {
      float tot = earr[0];
#pragma unroll
      for (int k = 1; k < NWAVE; ++k) tot += earr[k];
      out[0] = (float)(c + (double)g + (double)__logf(tot));
    }
  }
}

extern "C" void kernel_launch(void* const* d_in, const int* in_sizes, int n_in,
                              void* d_out, int out_size, void* d_ws, size_t ws_size,
                              hipStream_t stream) {
  const int* obs = (const int*)d_in[0];
  const float* start = (const float*)d_in[1];
  const float* trans = (const float*)d_in[2];
  const float* emit = (const float*)d_in[3];

  // ws layout: 0: rbuf[2][1024] u64 (16 KB) | 16384: Et 1024*1024 fp16 (2 MB)
  unsigned long long* rbuf = (unsigned long long*)d_ws;
  _Float16* Et = (_Float16*)((char*)d_ws + 16384);

  prep_E<<<dim3(32, 32), dim3(32, 32), 0, stream>>>(trans, Et);
  hmm_init<<<1, S, 0, stream>>>(obs, start, emit, rbuf);
  hmm_main<<<NWG, NTHR, 0, stream>>>(obs, emit, Et, rbuf, (float*)d_out);
}